// Round 1
// baseline (1337.555 us; speedup 1.0000x reference)
//
#include <hip/hip_runtime.h>

// Problem constants (B,T,D,H) = (4,4096,2048,128)
#define Bq 4
#define Tq 4096
#define Dq 2048
#define Hq 128
#define Mq (Bq*Tq)   // 16384 rows

// ---------------------------------------------------------------------------
// Kernel 1: QKV projection. out[w][m][h] = sum_k x[m][k] * W_w[k][h]
// grid: (Mq/32, 3), block 256. Tile: 32 rows x 128 cols, K-tile 64.
// ---------------------------------------------------------------------------
__global__ __launch_bounds__(256, 1) void qkv_proj_kernel(
    const float* __restrict__ x,
    const float* __restrict__ Wqp,
    const float* __restrict__ Wkp,
    const float* __restrict__ Wvp,
    float* __restrict__ qkv)
{
    __shared__ float xs[32][64];    // x tile
    __shared__ float ws[64][128];   // W tile

    const int m0 = blockIdx.x * 32;
    const int w  = blockIdx.y;
    const float* __restrict__ W = (w == 0) ? Wqp : (w == 1) ? Wkp : Wvp;
    float* __restrict__ out = qkv + (size_t)w * Mq * Hq;

    const int t  = threadIdx.x;
    const int tr = t >> 5;   // 0..7  -> rows tr*4 .. tr*4+3
    const int tc = t & 31;   // 0..31 -> cols tc, tc+32, tc+64, tc+96

    float acc[4][4] = {};

    for (int k0 = 0; k0 < Dq; k0 += 64) {
        // stage x tile: 32x64 = 512 float4, 2 per thread
        {
            int idx = t;
            #pragma unroll
            for (int i = 0; i < 2; i++, idx += 256) {
                int r = idx >> 4, c4 = idx & 15;
                *(float4*)&xs[r][c4 * 4] =
                    *(const float4*)&x[(size_t)(m0 + r) * Dq + k0 + c4 * 4];
            }
        }
        // stage W tile: 64x128 = 2048 float4, 8 per thread
        {
            int idx = t;
            #pragma unroll
            for (int i = 0; i < 8; i++, idx += 256) {
                int r = idx >> 5, c4 = idx & 31;
                *(float4*)&ws[r][c4 * 4] =
                    *(const float4*)&W[(size_t)(k0 + r) * Hq + c4 * 4];
            }
        }
        __syncthreads();
        #pragma unroll 8
        for (int kk = 0; kk < 64; kk++) {
            float a[4], b[4];
            #pragma unroll
            for (int i = 0; i < 4; i++) a[i] = xs[tr * 4 + i][kk];   // broadcast
            #pragma unroll
            for (int j = 0; j < 4; j++) b[j] = ws[kk][tc + 32 * j];  // stride-1 lanes
            #pragma unroll
            for (int i = 0; i < 4; i++)
                #pragma unroll
                for (int j = 0; j < 4; j++)
                    acc[i][j] = fmaf(a[i], b[j], acc[i][j]);
        }
        __syncthreads();
    }

    #pragma unroll
    for (int i = 0; i < 4; i++)
        #pragma unroll
        for (int j = 0; j < 4; j++)
            out[(size_t)(m0 + tr * 4 + i) * Hq + tc + 32 * j] = acc[i][j];
}

// ---------------------------------------------------------------------------
// Kernel 2: causal flash attention over materialized Q,K,V (fp32).
// grid: (Tq/64, Bq), block 256. Q-tile 64, K-tile 64, online softmax.
// ---------------------------------------------------------------------------
__global__ __launch_bounds__(256, 1) void attn_kernel(
    const float* __restrict__ qkv, float* __restrict__ outg)
{
    __shared__ float qs[64][128];   // Q tile (pre-scaled)
    __shared__ float ks[64][129];   // K tile, +1 pad: bank = (c+h)%32, conflict-free
    __shared__ float vs[64][128];   // V tile
    __shared__ float ss[64][65];    // scores / probabilities
    __shared__ float mcur[64], lrow[64], arow[64];
    __shared__ float pred[4][64];   // partial row reductions

    const int qt = blockIdx.x;
    const int b  = blockIdx.y;
    const int q0 = qt * 64;

    const float* __restrict__ Q = qkv + (size_t)b * Tq * Hq;
    const float* __restrict__ K = qkv + (size_t)Mq * Hq + (size_t)b * Tq * Hq;
    const float* __restrict__ V = qkv + 2 * (size_t)Mq * Hq + (size_t)b * Tq * Hq;

    const int t = threadIdx.x;
    const float scale = 0.08838834764831843f;  // 1/sqrt(128)

    // load Q tile, pre-scaled
    {
        int idx = t;
        #pragma unroll
        for (int i = 0; i < 8; i++, idx += 256) {
            int r = idx >> 5, c4 = idx & 31;
            float4 v = *(const float4*)&Q[(size_t)(q0 + r) * Hq + c4 * 4];
            v.x *= scale; v.y *= scale; v.z *= scale; v.w *= scale;
            *(float4*)&qs[r][c4 * 4] = v;
        }
    }
    if (t < 64) { mcur[t] = -1e30f; lrow[t] = 0.f; }

    // S-phase mapping: rows str*8+i (i<8), cols stc, stc+32
    const int str = t >> 5;
    const int stc = t & 31;
    // PV/O mapping: rows rg*4+jj (jj<4), cols cg+16*ii (ii<8)
    const int rg = t >> 4;
    const int cg = t & 15;

    float o[4][8] = {};

    for (int j0 = 0; j0 <= q0; j0 += 64) {
        __syncthreads();  // protect ks/vs/ss overwrite vs previous-tile readers

        // stage K (scalar stores: stride-129 rows) and V (float4)
        {
            int idx = t;
            #pragma unroll
            for (int i = 0; i < 8; i++, idx += 256) {
                int r = idx >> 5, c4 = idx & 31;
                float4 kv = *(const float4*)&K[(size_t)(j0 + r) * Hq + c4 * 4];
                ks[r][c4 * 4 + 0] = kv.x; ks[r][c4 * 4 + 1] = kv.y;
                ks[r][c4 * 4 + 2] = kv.z; ks[r][c4 * 4 + 3] = kv.w;
                *(float4*)&vs[r][c4 * 4] =
                    *(const float4*)&V[(size_t)(j0 + r) * Hq + c4 * 4];
            }
        }
        __syncthreads();

        // S = qs @ ks^T  (16 scores per thread)
        {
            float sacc[8][2] = {};
            for (int h = 0; h < 128; h += 4) {
                float4 a4[8];
                float bk[2][4];
                #pragma unroll
                for (int i = 0; i < 8; i++)
                    a4[i] = *(const float4*)&qs[str * 8 + i][h];
                #pragma unroll
                for (int j = 0; j < 2; j++) {
                    int c = stc + 32 * j;
                    bk[j][0] = ks[c][h];     bk[j][1] = ks[c][h + 1];
                    bk[j][2] = ks[c][h + 2]; bk[j][3] = ks[c][h + 3];
                }
                #pragma unroll
                for (int i = 0; i < 8; i++)
                    #pragma unroll
                    for (int j = 0; j < 2; j++) {
                        sacc[i][j] = fmaf(a4[i].x, bk[j][0], sacc[i][j]);
                        sacc[i][j] = fmaf(a4[i].y, bk[j][1], sacc[i][j]);
                        sacc[i][j] = fmaf(a4[i].z, bk[j][2], sacc[i][j]);
                        sacc[i][j] = fmaf(a4[i].w, bk[j][3], sacc[i][j]);
                    }
            }
            const bool diag = (j0 == q0);
            #pragma unroll
            for (int i = 0; i < 8; i++)
                #pragma unroll
                for (int j = 0; j < 2; j++) {
                    int r = str * 8 + i, c = stc + 32 * j;
                    float v = sacc[i][j];
                    if (diag && c > r) v = -1e30f;  // causal mask
                    ss[r][c] = v;
                }
        }
        __syncthreads();

        // pass1: partial row max (r = t&63, 16-col chunk = t>>6)
        {
            int rr = t & 63, ch = t >> 6;
            float mx = -1e30f;
            #pragma unroll
            for (int c = 0; c < 16; c++) mx = fmaxf(mx, ss[rr][ch * 16 + c]);
            pred[ch][rr] = mx;
        }
        __syncthreads();

        // pass2: combine max, alpha
        if (t < 64) {
            float mt = fmaxf(fmaxf(pred[0][t], pred[1][t]),
                             fmaxf(pred[2][t], pred[3][t]));
            float mnew = fmaxf(mcur[t], mt);
            arow[t] = __expf(mcur[t] - mnew);
            mcur[t] = mnew;
        }
        __syncthreads();

        // pass3: exponentiate in place, partial row sums
        {
            int rr = t & 63, ch = t >> 6;
            float sm = 0.f;
            #pragma unroll
            for (int c = 0; c < 16; c++) {
                float p = __expf(ss[rr][ch * 16 + c] - mcur[rr]);
                ss[rr][ch * 16 + c] = p;
                sm += p;
            }
            pred[ch][rr] = sm;
        }
        __syncthreads();

        // pass4: update running denominator
        if (t < 64) {
            lrow[t] = lrow[t] * arow[t] +
                      (pred[0][t] + pred[1][t] + pred[2][t] + pred[3][t]);
        }

        // PV: O = O*alpha + P @ V   (4 rows x 8 cols per thread)
        {
            float al[4];
            #pragma unroll
            for (int jj = 0; jj < 4; jj++) al[jj] = arow[rg * 4 + jj];
            #pragma unroll
            for (int jj = 0; jj < 4; jj++)
                #pragma unroll
                for (int ii = 0; ii < 8; ii++) o[jj][ii] *= al[jj];

            for (int s = 0; s < 64; s++) {
                float p[4], vv[8];
                #pragma unroll
                for (int jj = 0; jj < 4; jj++) p[jj] = ss[rg * 4 + jj][s];
                #pragma unroll
                for (int ii = 0; ii < 8; ii++) vv[ii] = vs[s][cg + 16 * ii];
                #pragma unroll
                for (int jj = 0; jj < 4; jj++)
                    #pragma unroll
                    for (int ii = 0; ii < 8; ii++)
                        o[jj][ii] = fmaf(p[jj], vv[ii], o[jj][ii]);
            }
        }
    }

    __syncthreads();
    // normalize + store
    #pragma unroll
    for (int jj = 0; jj < 4; jj++) {
        float inv = 1.0f / lrow[rg * 4 + jj];
        size_t row = (size_t)b * Tq + q0 + rg * 4 + jj;
        #pragma unroll
        for (int ii = 0; ii < 8; ii++)
            outg[row * Hq + cg + 16 * ii] = o[jj][ii] * inv;
    }
}

// ---------------------------------------------------------------------------
extern "C" void kernel_launch(void* const* d_in, const int* in_sizes, int n_in,
                              void* d_out, int out_size, void* d_ws, size_t ws_size,
                              hipStream_t stream) {
    const float* x   = (const float*)d_in[0];
    const float* Wqp = (const float*)d_in[1];
    const float* Wkp = (const float*)d_in[2];
    const float* Wvp = (const float*)d_in[3];
    float* out = (float*)d_out;
    float* qkv = (float*)d_ws;   // [3][Mq][Hq] fp32 = 25.2 MB

    dim3 g1(Mq / 32, 3);
    qkv_proj_kernel<<<g1, dim3(256), 0, stream>>>(x, Wqp, Wkp, Wvp, qkv);

    dim3 g2(Tq / 64, Bq);
    attn_kernel<<<g2, dim3(256), 0, stream>>>(qkv, out);
}

// Round 2
// 799.399 us; speedup vs baseline: 1.6732x; 1.6732x over previous
//
#include <hip/hip_runtime.h>
#include <hip/hip_bf16.h>

// Problem constants (B,T,D,H) = (4,4096,2048,128)
#define Bq 4
#define Tq 4096
#define Dq 2048
#define Hq 128
#define Mq (Bq*Tq)   // 16384 rows

typedef __attribute__((ext_vector_type(8))) short bf16x8;
typedef __attribute__((ext_vector_type(4))) float f32x4;

static __device__ __forceinline__ short bfbits(float f) {
    union { __hip_bfloat16 h; short s; } u;
    u.h = __float2bfloat16(f);
    return u.s;
}

// ---------------------------------------------------------------------------
// Kernel 1: QKV projection (UNCHANGED from round 1 — fp32 LDS-tiled).
// ---------------------------------------------------------------------------
__global__ __launch_bounds__(256, 1) void qkv_proj_kernel(
    const float* __restrict__ x,
    const float* __restrict__ Wqp,
    const float* __restrict__ Wkp,
    const float* __restrict__ Wvp,
    float* __restrict__ qkv)
{
    __shared__ float xs[32][64];
    __shared__ float ws[64][128];

    const int m0 = blockIdx.x * 32;
    const int w  = blockIdx.y;
    const float* __restrict__ W = (w == 0) ? Wqp : (w == 1) ? Wkp : Wvp;
    float* __restrict__ out = qkv + (size_t)w * Mq * Hq;

    const int t  = threadIdx.x;
    const int tr = t >> 5;
    const int tc = t & 31;

    float acc[4][4] = {};

    for (int k0 = 0; k0 < Dq; k0 += 64) {
        {
            int idx = t;
            #pragma unroll
            for (int i = 0; i < 2; i++, idx += 256) {
                int r = idx >> 4, c4 = idx & 15;
                *(float4*)&xs[r][c4 * 4] =
                    *(const float4*)&x[(size_t)(m0 + r) * Dq + k0 + c4 * 4];
            }
        }
        {
            int idx = t;
            #pragma unroll
            for (int i = 0; i < 8; i++, idx += 256) {
                int r = idx >> 5, c4 = idx & 31;
                *(float4*)&ws[r][c4 * 4] =
                    *(const float4*)&W[(size_t)(k0 + r) * Hq + c4 * 4];
            }
        }
        __syncthreads();
        #pragma unroll 8
        for (int kk = 0; kk < 64; kk++) {
            float a[4], b[4];
            #pragma unroll
            for (int i = 0; i < 4; i++) a[i] = xs[tr * 4 + i][kk];
            #pragma unroll
            for (int j = 0; j < 4; j++) b[j] = ws[kk][tc + 32 * j];
            #pragma unroll
            for (int i = 0; i < 4; i++)
                #pragma unroll
                for (int j = 0; j < 4; j++)
                    acc[i][j] = fmaf(a[i], b[j], acc[i][j]);
        }
        __syncthreads();
    }

    #pragma unroll
    for (int i = 0; i < 4; i++)
        #pragma unroll
        for (int j = 0; j < 4; j++)
            out[(size_t)(m0 + tr * 4 + i) * Hq + tc + 32 * j] = acc[i][j];
}

// ---------------------------------------------------------------------------
// Kernel 2: causal flash attention, bf16 MFMA (16x16x32), fp32 accumulate.
// grid (Tq/64, Bq), block 256 = 4 waves; wave qw owns q-rows [qw*16, qw*16+16).
// Verified layouts: A[m=lane&15][k=quad*8+j]; B[k=quad*8+j][n=lane&15];
//                   C/D row=quad*4+reg, col=lane&15.
// ---------------------------------------------------------------------------
__global__ __launch_bounds__(256, 2) void attn_mfma_kernel(
    const float* __restrict__ qkv, float* __restrict__ outg)
{
    __shared__ short qs[64][136];   // Q tile bf16, +8 pad (row stride 272B)
    __shared__ short ks[64][136];   // K tile bf16
    __shared__ short vt[128][72];   // V tile TRANSPOSED [h][s], +8 pad
    __shared__ short ps[64][72];    // P tile bf16 [q][s]

    const int q0 = blockIdx.x * 64;
    const int b  = blockIdx.y;
    const float* __restrict__ Q = qkv + (size_t)b * Tq * Hq;
    const float* __restrict__ K = qkv + (size_t)Mq * Hq + (size_t)b * Tq * Hq;
    const float* __restrict__ V = qkv + 2 * (size_t)Mq * Hq + (size_t)b * Tq * Hq;

    const int t    = threadIdx.x;
    const int lane = t & 63;
    const int qw   = t >> 6;       // wave id 0..3
    const int l15  = lane & 15;
    const int quad = lane >> 4;    // 0..3

    // ---- stage Q tile (pre-scaled), bf16 ----
    {
        const float scale = 0.08838834764831843f;  // 1/sqrt(128)
        int r = t >> 2, c0 = (t & 3) * 32;
        const float* src = Q + (size_t)(q0 + r) * Hq + c0;
        #pragma unroll
        for (int i = 0; i < 4; i++) {
            float4 f0 = *(const float4*)(src + i * 8);
            float4 f1 = *(const float4*)(src + i * 8 + 4);
            bf16x8 v;
            v[0] = bfbits(f0.x * scale); v[1] = bfbits(f0.y * scale);
            v[2] = bfbits(f0.z * scale); v[3] = bfbits(f0.w * scale);
            v[4] = bfbits(f1.x * scale); v[5] = bfbits(f1.y * scale);
            v[6] = bfbits(f1.z * scale); v[7] = bfbits(f1.w * scale);
            *(bf16x8*)&qs[r][c0 + i * 8] = v;
        }
    }

    float mcur[4], lrow[4];
    #pragma unroll
    for (int r = 0; r < 4; r++) { mcur[r] = -1e30f; lrow[r] = 0.f; }
    f32x4 o[8];
    #pragma unroll
    for (int nf = 0; nf < 8; nf++) o[nf] = (f32x4){0.f, 0.f, 0.f, 0.f};

    for (int j0 = 0; j0 <= q0; j0 += 64) {
        __syncthreads();   // previous tile's ks/vt readers done

        // ---- stage K tile bf16 ----
        {
            int r = t >> 2, c0 = (t & 3) * 32;
            const float* src = K + (size_t)(j0 + r) * Hq + c0;
            #pragma unroll
            for (int i = 0; i < 4; i++) {
                float4 f0 = *(const float4*)(src + i * 8);
                float4 f1 = *(const float4*)(src + i * 8 + 4);
                bf16x8 v;
                v[0] = bfbits(f0.x); v[1] = bfbits(f0.y);
                v[2] = bfbits(f0.z); v[3] = bfbits(f0.w);
                v[4] = bfbits(f1.x); v[5] = bfbits(f1.y);
                v[6] = bfbits(f1.z); v[7] = bfbits(f1.w);
                *(bf16x8*)&ks[r][c0 + i * 8] = v;
            }
        }
        // ---- stage V tile transposed: vt[h][s] ----
        {
            int s = t & 63, h0 = (t >> 6) * 32;
            const float* src = V + (size_t)(j0 + s) * Hq + h0;
            #pragma unroll
            for (int i = 0; i < 8; i++) {
                float4 f = *(const float4*)(src + i * 4);
                vt[h0 + i * 4 + 0][s] = bfbits(f.x);
                vt[h0 + i * 4 + 1][s] = bfbits(f.y);
                vt[h0 + i * 4 + 2][s] = bfbits(f.z);
                vt[h0 + i * 4 + 3][s] = bfbits(f.w);
            }
        }
        __syncthreads();

        // ---- S = Q K^T : 4 n-frags (64 keys), K-dim 128 = 4 MFMA steps ----
        f32x4 sacc[4];
        #pragma unroll
        for (int nf = 0; nf < 4; nf++) sacc[nf] = (f32x4){0.f, 0.f, 0.f, 0.f};
        #pragma unroll
        for (int kk = 0; kk < 4; kk++) {
            bf16x8 aq = *(bf16x8*)&qs[qw * 16 + l15][kk * 32 + quad * 8];
            #pragma unroll
            for (int nf = 0; nf < 4; nf++) {
                bf16x8 bk = *(bf16x8*)&ks[nf * 16 + l15][kk * 32 + quad * 8];
                sacc[nf] = __builtin_amdgcn_mfma_f32_16x16x32_bf16(aq, bk, sacc[nf], 0, 0, 0);
            }
        }

        const bool diag = (j0 == q0);
        // ---- online softmax, registers + width-16 shuffles ----
        #pragma unroll
        for (int reg = 0; reg < 4; reg++) {
            const int rloc = qw * 16 + quad * 4 + reg;   // q-row within tile
            if (diag) {
                #pragma unroll
                for (int nf = 0; nf < 4; nf++)
                    if (nf * 16 + l15 > rloc) sacc[nf][reg] = -1e30f;
            }
            float m_r = fmaxf(fmaxf(sacc[0][reg], sacc[1][reg]),
                              fmaxf(sacc[2][reg], sacc[3][reg]));
            #pragma unroll
            for (int mm = 8; mm >= 1; mm >>= 1)
                m_r = fmaxf(m_r, __shfl_xor(m_r, mm, 16));
            float mnew  = fmaxf(mcur[reg], m_r);
            float alpha = __expf(mcur[reg] - mnew);
            mcur[reg]   = mnew;
            float rs = 0.f;
            #pragma unroll
            for (int nf = 0; nf < 4; nf++) {
                float p = __expf(sacc[nf][reg] - mnew);
                rs += p;
                ps[rloc][nf * 16 + l15] = bfbits(p);
            }
            #pragma unroll
            for (int mm = 8; mm >= 1; mm >>= 1)
                rs += __shfl_xor(rs, mm, 16);
            lrow[reg] = lrow[reg] * alpha + rs;
            #pragma unroll
            for (int nf = 0; nf < 8; nf++) o[nf][reg] *= alpha;
        }
        __threadfence_block();   // order ps writes before same-wave ds reads

        // ---- O += P V : 8 n-frags (128 h), K-dim 64 = 2 MFMA steps ----
        #pragma unroll
        for (int ks2 = 0; ks2 < 2; ks2++) {
            bf16x8 ap = *(bf16x8*)&ps[qw * 16 + l15][ks2 * 32 + quad * 8];
            #pragma unroll
            for (int nf = 0; nf < 8; nf++) {
                bf16x8 bv = *(bf16x8*)&vt[nf * 16 + l15][ks2 * 32 + quad * 8];
                o[nf] = __builtin_amdgcn_mfma_f32_16x16x32_bf16(ap, bv, o[nf], 0, 0, 0);
            }
        }
    }

    // ---- epilogue: normalize + store fp32 ----
    #pragma unroll
    for (int reg = 0; reg < 4; reg++) {
        float inv = 1.0f / lrow[reg];
        size_t row = (size_t)b * Tq + q0 + qw * 16 + quad * 4 + reg;
        #pragma unroll
        for (int nf = 0; nf < 8; nf++)
            outg[row * Hq + nf * 16 + l15] = o[nf][reg] * inv;
    }
}

// ---------------------------------------------------------------------------
extern "C" void kernel_launch(void* const* d_in, const int* in_sizes, int n_in,
                              void* d_out, int out_size, void* d_ws, size_t ws_size,
                              hipStream_t stream) {
    const float* x   = (const float*)d_in[0];
    const float* Wqp = (const float*)d_in[1];
    const float* Wkp = (const float*)d_in[2];
    const float* Wvp = (const float*)d_in[3];
    float* out = (float*)d_out;
    float* qkv = (float*)d_ws;   // [3][Mq][Hq] fp32 = 25.2 MB

    dim3 g1(Mq / 32, 3);
    qkv_proj_kernel<<<g1, dim3(256), 0, stream>>>(x, Wqp, Wkp, Wvp, qkv);

    dim3 g2(Tq / 64, Bq);
    attn_mfma_kernel<<<g2, dim3(256), 0, stream>>>(qkv, out);
}

// Round 3
// 414.647 us; speedup vs baseline: 3.2258x; 1.9279x over previous
//
#include <hip/hip_runtime.h>
#include <hip/hip_bf16.h>

// Problem constants (B,T,D,H) = (4,4096,2048,128)
#define Bq 4
#define Tq 4096
#define Dq 2048
#define Hq 128
#define Mq (Bq*Tq)   // 16384 rows

typedef __attribute__((ext_vector_type(8))) short bf16x8;
typedef __attribute__((ext_vector_type(4))) float f32x4;

static __device__ __forceinline__ short bfbits(float f) {
    union { __hip_bfloat16 h; short s; } u;
    u.h = __float2bfloat16(f);
    return u.s;
}

// ---------------------------------------------------------------------------
// Kernel 0: W transpose+convert.  W[w] fp32 [2048][128] -> wT[w] bf16 [128][2048].
// Scale 1/sqrt(128) folded into w==0 (Wq).  grid (16,3), block 256.
// ---------------------------------------------------------------------------
__global__ __launch_bounds__(256, 1) void wt_kernel(
    const float* __restrict__ Wqp,
    const float* __restrict__ Wkp,
    const float* __restrict__ Wvp,
    short* __restrict__ wTg)          // [3][128][2048]
{
    __shared__ short trsp[128][136];  // [h][k-local], +8 pad
    const int kc = blockIdx.x;        // k-chunk of 128
    const int w  = blockIdx.y;
    const float* __restrict__ W = (w == 0) ? Wqp : (w == 1) ? Wkp : Wvp;
    const float scale = (w == 0) ? 0.08838834764831843f : 1.0f;
    const int t = threadIdx.x;

    #pragma unroll
    for (int i = 0; i < 16; i++) {
        int idx = t + i * 256;
        int r = idx >> 5, c4 = idx & 31;          // k-row r, h-col block c4
        float4 f = *(const float4*)&W[(size_t)(kc * 128 + r) * Hq + c4 * 4];
        trsp[c4 * 4 + 0][r] = bfbits(f.x * scale);
        trsp[c4 * 4 + 1][r] = bfbits(f.y * scale);
        trsp[c4 * 4 + 2][r] = bfbits(f.z * scale);
        trsp[c4 * 4 + 3][r] = bfbits(f.w * scale);
    }
    __syncthreads();
    #pragma unroll
    for (int i = 0; i < 8; i++) {
        int idx = t + i * 256;
        int h = idx >> 4, c8 = idx & 15;          // 16B chunk c8 of k
        *(bf16x8*)&wTg[((size_t)w * 128 + h) * Dq + kc * 128 + c8 * 8] =
            *(bf16x8*)&trsp[h][c8 * 8];
    }
}

// ---------------------------------------------------------------------------
// Kernel 1: QKV projection, bf16 MFMA.  out = x @ W  (q pre-scaled).
// grid (3, Mq/64), block 256.  M-tile 64, N-tile 128, BK 64.
// q,k written row-major bf16 [M][128]; v written TRANSPOSED vT[b][128][4096].
// ---------------------------------------------------------------------------
__global__ __launch_bounds__(256, 3) void qkv_mfma_kernel(
    const float* __restrict__ x,
    const short* __restrict__ wTg,    // [3][128][2048] bf16
    short* __restrict__ qg,           // [Mq][128] bf16
    short* __restrict__ kg,           // [Mq][128] bf16
    short* __restrict__ vTg)          // [Bq][128][Tq] bf16
{
    __shared__ short xs[64][72];      // x tile bf16 [m][k], +8 pad
    __shared__ short wt[128][72];     // W tile bf16 [n][k], +8 pad
    __shared__ short epi[128 * 72];   // epilogue staging (two views)

    const int w  = blockIdx.x;        // 0=q 1=k 2=v
    const int m0 = blockIdx.y * 64;
    const short* __restrict__ wT = wTg + (size_t)w * 128 * Dq;

    const int t    = threadIdx.x;
    const int lane = t & 63;
    const int qw   = t >> 6;
    const int l15  = lane & 15;
    const int quad = lane >> 4;

    f32x4 o[8];
    #pragma unroll
    for (int nf = 0; nf < 8; nf++) o[nf] = (f32x4){0.f, 0.f, 0.f, 0.f};

    // staging maps
    const int xr = t >> 2, xc = (t & 3) * 16;   // x: 16 floats/thread
    const int wr = t >> 1, wc = (t & 1) * 32;   // wT: 32 bf16/thread

    for (int k0 = 0; k0 < Dq; k0 += 64) {
        __syncthreads();
        // stage x fp32 -> bf16
        {
            const float* src = x + (size_t)(m0 + xr) * Dq + k0 + xc;
            float4 f0 = *(const float4*)(src + 0);
            float4 f1 = *(const float4*)(src + 4);
            float4 f2 = *(const float4*)(src + 8);
            float4 f3 = *(const float4*)(src + 12);
            bf16x8 v0, v1;
            v0[0] = bfbits(f0.x); v0[1] = bfbits(f0.y); v0[2] = bfbits(f0.z); v0[3] = bfbits(f0.w);
            v0[4] = bfbits(f1.x); v0[5] = bfbits(f1.y); v0[6] = bfbits(f1.z); v0[7] = bfbits(f1.w);
            v1[0] = bfbits(f2.x); v1[1] = bfbits(f2.y); v1[2] = bfbits(f2.z); v1[3] = bfbits(f2.w);
            v1[4] = bfbits(f3.x); v1[5] = bfbits(f3.y); v1[6] = bfbits(f3.z); v1[7] = bfbits(f3.w);
            *(bf16x8*)&xs[xr][xc]     = v0;
            *(bf16x8*)&xs[xr][xc + 8] = v1;
        }
        // stage wT bf16 copy
        {
            const short* src = wT + (size_t)wr * Dq + k0 + wc;
            #pragma unroll
            for (int i = 0; i < 4; i++)
                *(bf16x8*)&wt[wr][wc + i * 8] = *(const bf16x8*)(src + i * 8);
        }
        __syncthreads();

        #pragma unroll
        for (int kk = 0; kk < 2; kk++) {
            bf16x8 a = *(bf16x8*)&xs[qw * 16 + l15][kk * 32 + quad * 8];
            #pragma unroll
            for (int nf = 0; nf < 8; nf++) {
                bf16x8 b = *(bf16x8*)&wt[nf * 16 + l15][kk * 32 + quad * 8];
                o[nf] = __builtin_amdgcn_mfma_f32_16x16x32_bf16(a, b, o[nf], 0, 0, 0);
            }
        }
    }

    __syncthreads();
    if (w < 2) {
        // row-major epilogue: e64[m][h]
        short (*e64)[136] = (short(*)[136])epi;
        #pragma unroll
        for (int nf = 0; nf < 8; nf++)
            #pragma unroll
            for (int reg = 0; reg < 4; reg++)
                e64[qw * 16 + quad * 4 + reg][nf * 16 + l15] = bfbits(o[nf][reg]);
        __syncthreads();
        short* outp = (w == 0) ? qg : kg;
        #pragma unroll
        for (int i = 0; i < 4; i++) {
            int idx = t + i * 256;
            int r = idx >> 4, c = idx & 15;
            *(bf16x8*)&outp[(size_t)(m0 + r) * Hq + c * 8] = *(bf16x8*)&e64[r][c * 8];
        }
    } else {
        // transposed epilogue: e128[h][m]  (in-lane regs are consecutive rows m)
        short (*e128)[72] = (short(*)[72])epi;
        #pragma unroll
        for (int nf = 0; nf < 8; nf++) {
            short4 pk;
            pk.x = bfbits(o[nf][0]); pk.y = bfbits(o[nf][1]);
            pk.z = bfbits(o[nf][2]); pk.w = bfbits(o[nf][3]);
            *(short4*)&e128[nf * 16 + l15][qw * 16 + quad * 4] = pk;
        }
        __syncthreads();
        const int b  = m0 / Tq;
        const int t0 = m0 % Tq;
        #pragma unroll
        for (int i = 0; i < 4; i++) {
            int idx = t + i * 256;
            int h = idx >> 3, c = idx & 7;
            *(bf16x8*)&vTg[((size_t)b * 128 + h) * Tq + t0 + c * 8] =
                *(bf16x8*)&e128[h][c * 8];
        }
    }
}

// ---------------------------------------------------------------------------
// Kernel 2: causal flash attention, bf16 MFMA — staging is now pure bf16 copy.
// grid (Tq/64, Bq), block 256.
// ---------------------------------------------------------------------------
__global__ __launch_bounds__(256, 2) void attn_mfma_kernel(
    const short* __restrict__ qg, const short* __restrict__ kg,
    const short* __restrict__ vTg, float* __restrict__ outg)
{
    __shared__ short qs[64][136];
    __shared__ short ks[64][136];
    __shared__ short vt[128][72];
    __shared__ short ps[64][72];

    const int q0 = blockIdx.x * 64;
    const int b  = blockIdx.y;

    const int t    = threadIdx.x;
    const int lane = t & 63;
    const int qw   = t >> 6;
    const int l15  = lane & 15;
    const int quad = lane >> 4;

    // stage Q (already scaled, bf16)
    {
        int r = t >> 2, c0 = (t & 3) * 32;
        const short* src = qg + (size_t)(b * Tq + q0 + r) * Hq + c0;
        #pragma unroll
        for (int i = 0; i < 4; i++)
            *(bf16x8*)&qs[r][c0 + i * 8] = *(const bf16x8*)(src + i * 8);
    }

    float mcur[4], lrow[4];
    #pragma unroll
    for (int r = 0; r < 4; r++) { mcur[r] = -1e30f; lrow[r] = 0.f; }
    f32x4 o[8];
    #pragma unroll
    for (int nf = 0; nf < 8; nf++) o[nf] = (f32x4){0.f, 0.f, 0.f, 0.f};

    for (int j0 = 0; j0 <= q0; j0 += 64) {
        __syncthreads();

        // stage K tile (bf16 copy)
        {
            int r = t >> 2, c0 = (t & 3) * 32;
            const short* src = kg + (size_t)(b * Tq + j0 + r) * Hq + c0;
            #pragma unroll
            for (int i = 0; i < 4; i++)
                *(bf16x8*)&ks[r][c0 + i * 8] = *(const bf16x8*)(src + i * 8);
        }
        // stage V tile from pre-transposed vT (bf16 copy)
        {
            int h = t >> 1, s0 = (t & 1) * 32;
            const short* src = vTg + ((size_t)b * 128 + h) * Tq + j0 + s0;
            #pragma unroll
            for (int i = 0; i < 4; i++)
                *(bf16x8*)&vt[h][s0 + i * 8] = *(const bf16x8*)(src + i * 8);
        }
        __syncthreads();

        // S = Q K^T
        f32x4 sacc[4];
        #pragma unroll
        for (int nf = 0; nf < 4; nf++) sacc[nf] = (f32x4){0.f, 0.f, 0.f, 0.f};
        #pragma unroll
        for (int kk = 0; kk < 4; kk++) {
            bf16x8 aq = *(bf16x8*)&qs[qw * 16 + l15][kk * 32 + quad * 8];
            #pragma unroll
            for (int nf = 0; nf < 4; nf++) {
                bf16x8 bk = *(bf16x8*)&ks[nf * 16 + l15][kk * 32 + quad * 8];
                sacc[nf] = __builtin_amdgcn_mfma_f32_16x16x32_bf16(aq, bk, sacc[nf], 0, 0, 0);
            }
        }

        const bool diag = (j0 == q0);
        // online softmax (registers + width-16 shuffles)
        #pragma unroll
        for (int reg = 0; reg < 4; reg++) {
            const int rloc = qw * 16 + quad * 4 + reg;
            if (diag) {
                #pragma unroll
                for (int nf = 0; nf < 4; nf++)
                    if (nf * 16 + l15 > rloc) sacc[nf][reg] = -1e30f;
            }
            float m_r = fmaxf(fmaxf(sacc[0][reg], sacc[1][reg]),
                              fmaxf(sacc[2][reg], sacc[3][reg]));
            #pragma unroll
            for (int mm = 8; mm >= 1; mm >>= 1)
                m_r = fmaxf(m_r, __shfl_xor(m_r, mm, 16));
            float mnew  = fmaxf(mcur[reg], m_r);
            float alpha = __expf(mcur[reg] - mnew);
            mcur[reg]   = mnew;
            float rs = 0.f;
            #pragma unroll
            for (int nf = 0; nf < 4; nf++) {
                float p = __expf(sacc[nf][reg] - mnew);
                rs += p;
                ps[rloc][nf * 16 + l15] = bfbits(p);
            }
            #pragma unroll
            for (int mm = 8; mm >= 1; mm >>= 1)
                rs += __shfl_xor(rs, mm, 16);
            lrow[reg] = lrow[reg] * alpha + rs;
            #pragma unroll
            for (int nf = 0; nf < 8; nf++) o[nf][reg] *= alpha;
        }
        __threadfence_block();

        // O += P V
        #pragma unroll
        for (int ks2 = 0; ks2 < 2; ks2++) {
            bf16x8 ap = *(bf16x8*)&ps[qw * 16 + l15][ks2 * 32 + quad * 8];
            #pragma unroll
            for (int nf = 0; nf < 8; nf++) {
                bf16x8 bv = *(bf16x8*)&vt[nf * 16 + l15][ks2 * 32 + quad * 8];
                o[nf] = __builtin_amdgcn_mfma_f32_16x16x32_bf16(ap, bv, o[nf], 0, 0, 0);
            }
        }
    }

    // epilogue: normalize + store fp32
    #pragma unroll
    for (int reg = 0; reg < 4; reg++) {
        float inv = 1.0f / lrow[reg];
        size_t row = (size_t)b * Tq + q0 + qw * 16 + quad * 4 + reg;
        #pragma unroll
        for (int nf = 0; nf < 8; nf++)
            outg[row * Hq + nf * 16 + l15] = o[nf][reg] * inv;
    }
}

// ---------------------------------------------------------------------------
extern "C" void kernel_launch(void* const* d_in, const int* in_sizes, int n_in,
                              void* d_out, int out_size, void* d_ws, size_t ws_size,
                              hipStream_t stream) {
    const float* x   = (const float*)d_in[0];
    const float* Wqp = (const float*)d_in[1];
    const float* Wkp = (const float*)d_in[2];
    const float* Wvp = (const float*)d_in[3];
    float* out = (float*)d_out;

    // workspace layout (bf16 shorts)
    short* qg  = (short*)d_ws;                       // [Mq][128]   4 MB
    short* kg  = qg  + (size_t)Mq * Hq;              // [Mq][128]   4 MB
    short* vTg = kg  + (size_t)Mq * Hq;              // [Bq][128][Tq] 4 MB
    short* wTg = vTg + (size_t)Bq * Hq * Tq;         // [3][128][2048] 1.5 MB

    wt_kernel<<<dim3(16, 3), dim3(256), 0, stream>>>(Wqp, Wkp, Wvp, wTg);
    qkv_mfma_kernel<<<dim3(3, Mq / 64), dim3(256), 0, stream>>>(x, wTg, qg, kg, vTg);
    attn_mfma_kernel<<<dim3(Tq / 64, Bq), dim3(256), 0, stream>>>(qg, kg, vTg, out);
}

// Round 4
// 330.888 us; speedup vs baseline: 4.0423x; 1.2531x over previous
//
#include <hip/hip_runtime.h>
#include <hip/hip_bf16.h>

// Problem constants (B,T,D,H) = (4,4096,2048,128)
#define Bq 4
#define Tq 4096
#define Dq 2048
#define Hq 128
#define Mq (Bq*Tq)   // 16384 rows

typedef __attribute__((ext_vector_type(8))) short bf16x8;
typedef __attribute__((ext_vector_type(4))) float f32x4;

static __device__ __forceinline__ short bfbits(float f) {
    union { __hip_bfloat16 h; short s; } u;
    u.h = __float2bfloat16(f);
    return u.s;
}
static __device__ __forceinline__ float bf2f(short s) {
    union { unsigned u; float f; } v;
    v.u = ((unsigned)(unsigned short)s) << 16;
    return v.f;
}

// ---------------------------------------------------------------------------
// Kernel 0: W transpose+convert.  W[w] fp32 [2048][128] -> wT[w] bf16 [128][2048].
// Scale 1/sqrt(128) folded into w==0 (Wq).  grid (16,3), block 256.
// ---------------------------------------------------------------------------
__global__ __launch_bounds__(256, 1) void wt_kernel(
    const float* __restrict__ Wqp,
    const float* __restrict__ Wkp,
    const float* __restrict__ Wvp,
    short* __restrict__ wTg)          // [3][128][2048]
{
    __shared__ short trsp[128][136];
    const int kc = blockIdx.x;
    const int w  = blockIdx.y;
    const float* __restrict__ W = (w == 0) ? Wqp : (w == 1) ? Wkp : Wvp;
    const float scale = (w == 0) ? 0.08838834764831843f : 1.0f;
    const int t = threadIdx.x;

    #pragma unroll
    for (int i = 0; i < 16; i++) {
        int idx = t + i * 256;
        int r = idx >> 5, c4 = idx & 31;
        float4 f = *(const float4*)&W[(size_t)(kc * 128 + r) * Hq + c4 * 4];
        trsp[c4 * 4 + 0][r] = bfbits(f.x * scale);
        trsp[c4 * 4 + 1][r] = bfbits(f.y * scale);
        trsp[c4 * 4 + 2][r] = bfbits(f.z * scale);
        trsp[c4 * 4 + 3][r] = bfbits(f.w * scale);
    }
    __syncthreads();
    #pragma unroll
    for (int i = 0; i < 8; i++) {
        int idx = t + i * 256;
        int h = idx >> 4, c8 = idx & 15;
        *(bf16x8*)&wTg[((size_t)w * 128 + h) * Dq + kc * 128 + c8 * 8] =
            *(bf16x8*)&trsp[h][c8 * 8];
    }
}

// ---------------------------------------------------------------------------
// Kernel 1: QKV projection, bf16 MFMA, 128x128 tile (m97-style).
// grid (3, Mq/128), block 256 = 4 waves; wave (wm,wn) covers M64 x N64.
// q,k -> row-major bf16 [Mq][128]; v -> TILED transposed vTt[b][jt][128][64].
// ---------------------------------------------------------------------------
__global__ __launch_bounds__(256, 2) void qkv_mfma_kernel(
    const float* __restrict__ x,
    const short* __restrict__ wTg,    // [3][128][2048] bf16
    short* __restrict__ qg,           // [Mq][128]
    short* __restrict__ kg,           // [Mq][128]
    short* __restrict__ vTt)          // [Bq][Tq/64][128][64]
{
    __shared__ short smem[2 * 128 * 72];          // 36 KB, reused by epilogue
    short (*xs)[72]  = (short(*)[72])smem;        // x tile [m][k]
    short (*wts)[72] = (short(*)[72])(smem + 128 * 72);  // W tile [n][k]

    const int w  = blockIdx.x;
    const int m0 = blockIdx.y * 128;
    const short* __restrict__ wT = wTg + (size_t)w * 128 * Dq;

    const int t    = threadIdx.x;
    const int lane = t & 63;
    const int qw   = t >> 6;
    const int l15  = lane & 15;
    const int quad = lane >> 4;
    const int wm   = (qw >> 1) * 64;
    const int wn   = (qw & 1) * 64;

    f32x4 o[4][4];
    #pragma unroll
    for (int mf = 0; mf < 4; mf++)
        #pragma unroll
        for (int nf = 0; nf < 4; nf++) o[mf][nf] = (f32x4){0.f, 0.f, 0.f, 0.f};

    // staging maps (dense, idx-linear)
    const int xr = t >> 4, xc = (t & 15) * 4;   // x: 16 lanes/row, 8 row-steps
    const int wr = t >> 3, wu = (t & 7) * 8;    // wT: 8 lanes/row, 4 row-steps

    for (int k0 = 0; k0 < Dq; k0 += 64) {
        __syncthreads();
        // stage x fp32 -> bf16 : 128 rows x 64 k
        #pragma unroll
        for (int i = 0; i < 8; i++) {
            float4 f = *(const float4*)&x[(size_t)(m0 + xr + i * 16) * Dq + k0 + xc];
            short4 p;
            p.x = bfbits(f.x); p.y = bfbits(f.y); p.z = bfbits(f.z); p.w = bfbits(f.w);
            *(short4*)&xs[xr + i * 16][xc] = p;
        }
        // stage wT bf16 copy : 128 rows x 64 k
        #pragma unroll
        for (int i = 0; i < 4; i++)
            *(bf16x8*)&wts[wr + i * 32][wu] =
                *(const bf16x8*)&wT[(size_t)(wr + i * 32) * Dq + k0 + wu];
        __syncthreads();

        #pragma unroll
        for (int kk = 0; kk < 2; kk++) {
            bf16x8 a[4], b[4];
            #pragma unroll
            for (int mf = 0; mf < 4; mf++)
                a[mf] = *(bf16x8*)&xs[wm + mf * 16 + l15][kk * 32 + quad * 8];
            #pragma unroll
            for (int nf = 0; nf < 4; nf++)
                b[nf] = *(bf16x8*)&wts[wn + nf * 16 + l15][kk * 32 + quad * 8];
            #pragma unroll
            for (int mf = 0; mf < 4; mf++)
                #pragma unroll
                for (int nf = 0; nf < 4; nf++)
                    o[mf][nf] = __builtin_amdgcn_mfma_f32_16x16x32_bf16(
                        a[mf], b[nf], o[mf][nf], 0, 0, 0);
        }
    }

    __syncthreads();
    if (w < 2) {
        // row-major epilogue via LDS: e64[m 0..127][h 0..127]
        short (*e64)[136] = (short(*)[136])smem;
        #pragma unroll
        for (int mf = 0; mf < 4; mf++)
            #pragma unroll
            for (int nf = 0; nf < 4; nf++)
                #pragma unroll
                for (int reg = 0; reg < 4; reg++)
                    e64[wm + mf * 16 + quad * 4 + reg][wn + nf * 16 + l15] =
                        bfbits(o[mf][nf][reg]);
        __syncthreads();
        short* outp = (w == 0) ? qg : kg;
        #pragma unroll
        for (int i = 0; i < 8; i++) {
            int idx = t + i * 256;
            int r = idx >> 4, c = idx & 15;
            *(bf16x8*)&outp[(size_t)(m0 + r) * Hq + c * 8] = *(bf16x8*)&e64[r][c * 8];
        }
    } else {
        // transposed epilogue: e128[h][m-local 128], then 2 contiguous 16KB tiles
        short (*e128)[136] = (short(*)[136])smem;
        #pragma unroll
        for (int mf = 0; mf < 4; mf++)
            #pragma unroll
            for (int nf = 0; nf < 4; nf++) {
                short4 pk;
                pk.x = bfbits(o[mf][nf][0]); pk.y = bfbits(o[mf][nf][1]);
                pk.z = bfbits(o[mf][nf][2]); pk.w = bfbits(o[mf][nf][3]);
                *(short4*)&e128[wn + nf * 16 + l15][wm + mf * 16 + quad * 4] = pk;
            }
        __syncthreads();
        const int b   = m0 / Tq;
        const int jt0 = (m0 % Tq) / 64;
        #pragma unroll
        for (int i = 0; i < 8; i++) {
            int idx = t + i * 256;            // 2048 x 16B units
            int h = idx >> 4, u = idx & 15;
            int jt = u >> 3, uu = u & 7;
            *(bf16x8*)&vTt[((((size_t)b * (Tq / 64) + jt0 + jt) * 128) + h) * 64 + uu * 8] =
                *(bf16x8*)&e128[h][u * 8];
        }
    }
}

// ---------------------------------------------------------------------------
// Kernel 2: causal flash attention partials, split-K x2.
// grid (Tq/64, Bq, 2), block 256.  z halves the key-tile range; partial
// (unnormalized O bf16, m/l fp32) written for a later merge.
// Register prefetch of next K/V tile hides global latency under compute.
// ---------------------------------------------------------------------------
__global__ __launch_bounds__(256, 2) void attn_part_kernel(
    const short* __restrict__ qg, const short* __restrict__ kg,
    const short* __restrict__ vTt,
    short* __restrict__ Opart,        // [2][Mq][128] bf16 (unnormalized)
    float2* __restrict__ ml)          // [2][Mq] (m, l)
{
    __shared__ short qs[64][136];
    __shared__ short ks[64][136];
    __shared__ short vt[128][72];
    __shared__ short ps[64][72];

    const int qt = blockIdx.x;
    const int b  = blockIdx.y;
    const int z  = blockIdx.z;
    const int q0 = qt * 64;

    const int nj = qt + 1;
    const int half = nj >> 1;
    const int lo = z ? half : 0;
    const int hi = z ? nj : half;

    const int t    = threadIdx.x;
    const int lane = t & 63;
    const int qw   = t >> 6;
    const int l15  = lane & 15;
    const int quad = lane >> 4;

    const size_t zoff = (size_t)z * Mq;

    if (lo >= hi) {
        // empty partial: zero O, m=-1e30, l=0
        #pragma unroll
        for (int i = 0; i < 4; i++) {
            int idx = t + i * 256;
            int r = idx >> 4, c = idx & 15;
            bf16x8 zv = {0, 0, 0, 0, 0, 0, 0, 0};
            *(bf16x8*)&Opart[(zoff + (size_t)b * Tq + q0 + r) * Hq + c * 8] = zv;
        }
        if (t < 64) ml[zoff + (size_t)b * Tq + q0 + t] = make_float2(-1e30f, 0.f);
        return;
    }

    // stage Q tile (dense idx map)
    #pragma unroll
    for (int i = 0; i < 4; i++) {
        int idx = t + i * 256;
        int r = idx >> 4, c = idx & 15;
        *(bf16x8*)&qs[r][c * 8] =
            *(const bf16x8*)&qg[(size_t)(b * Tq + q0 + r) * Hq + c * 8];
    }

    float mcur[4], lrow[4];
    #pragma unroll
    for (int r = 0; r < 4; r++) { mcur[r] = -1e30f; lrow[r] = 0.f; }
    f32x4 o[8];
    #pragma unroll
    for (int nf = 0; nf < 8; nf++) o[nf] = (f32x4){0.f, 0.f, 0.f, 0.f};

    // prefetch regs for first tile
    bf16x8 kreg[4], vreg[4];
    {
        const size_t kbase = (size_t)(b * Tq + lo * 64) * Hq;
        const short* vsrc = vTt + (((size_t)b * (Tq / 64) + lo) * 128) * 64;
        #pragma unroll
        for (int i = 0; i < 4; i++) {
            int idx = t + i * 256;
            kreg[i] = *(const bf16x8*)&kg[kbase + (size_t)(idx >> 4) * Hq + (idx & 15) * 8];
            vreg[i] = *(const bf16x8*)&vsrc[idx * 8];
        }
    }

    for (int jt = lo; jt < hi; jt++) {
        __syncthreads();   // previous iter's readers of ks/vt done

        // write prefetched regs to LDS
        #pragma unroll
        for (int i = 0; i < 4; i++) {
            int idx = t + i * 256;
            *(bf16x8*)&ks[idx >> 4][(idx & 15) * 8] = kreg[i];
            *(bf16x8*)&vt[idx >> 3][(idx & 7) * 8]  = vreg[i];
        }
        // prefetch next tile
        if (jt + 1 < hi) {
            const size_t kbase = (size_t)(b * Tq + (jt + 1) * 64) * Hq;
            const short* vsrc = vTt + (((size_t)b * (Tq / 64) + jt + 1) * 128) * 64;
            #pragma unroll
            for (int i = 0; i < 4; i++) {
                int idx = t + i * 256;
                kreg[i] = *(const bf16x8*)&kg[kbase + (size_t)(idx >> 4) * Hq + (idx & 15) * 8];
                vreg[i] = *(const bf16x8*)&vsrc[idx * 8];
            }
        }
        __syncthreads();

        // S = Q K^T
        f32x4 sacc[4];
        #pragma unroll
        for (int nf = 0; nf < 4; nf++) sacc[nf] = (f32x4){0.f, 0.f, 0.f, 0.f};
        #pragma unroll
        for (int kk = 0; kk < 4; kk++) {
            bf16x8 aq = *(bf16x8*)&qs[qw * 16 + l15][kk * 32 + quad * 8];
            #pragma unroll
            for (int nf = 0; nf < 4; nf++) {
                bf16x8 bk = *(bf16x8*)&ks[nf * 16 + l15][kk * 32 + quad * 8];
                sacc[nf] = __builtin_amdgcn_mfma_f32_16x16x32_bf16(aq, bk, sacc[nf], 0, 0, 0);
            }
        }

        const bool diag = (jt == qt);
        #pragma unroll
        for (int reg = 0; reg < 4; reg++) {
            const int rloc = qw * 16 + quad * 4 + reg;
            if (diag) {
                #pragma unroll
                for (int nf = 0; nf < 4; nf++)
                    if (nf * 16 + l15 > rloc) sacc[nf][reg] = -1e30f;
            }
            float m_r = fmaxf(fmaxf(sacc[0][reg], sacc[1][reg]),
                              fmaxf(sacc[2][reg], sacc[3][reg]));
            #pragma unroll
            for (int mm = 8; mm >= 1; mm >>= 1)
                m_r = fmaxf(m_r, __shfl_xor(m_r, mm, 16));
            float mnew  = fmaxf(mcur[reg], m_r);
            float alpha = __expf(mcur[reg] - mnew);
            mcur[reg]   = mnew;
            float rs = 0.f;
            #pragma unroll
            for (int nf = 0; nf < 4; nf++) {
                float p = __expf(sacc[nf][reg] - mnew);
                rs += p;
                ps[rloc][nf * 16 + l15] = bfbits(p);
            }
            #pragma unroll
            for (int mm = 8; mm >= 1; mm >>= 1)
                rs += __shfl_xor(rs, mm, 16);
            lrow[reg] = lrow[reg] * alpha + rs;
            #pragma unroll
            for (int nf = 0; nf < 8; nf++) o[nf][reg] *= alpha;
        }
        __threadfence_block();

        // O += P V
        #pragma unroll
        for (int ks2 = 0; ks2 < 2; ks2++) {
            bf16x8 ap = *(bf16x8*)&ps[qw * 16 + l15][ks2 * 32 + quad * 8];
            #pragma unroll
            for (int nf = 0; nf < 8; nf++) {
                bf16x8 bv = *(bf16x8*)&vt[nf * 16 + l15][ks2 * 32 + quad * 8];
                o[nf] = __builtin_amdgcn_mfma_f32_16x16x32_bf16(ap, bv, o[nf], 0, 0, 0);
            }
        }
    }

    // epilogue: write unnormalized bf16 partial via LDS transpose (reuse ks)
    __syncthreads();
    #pragma unroll
    for (int nf = 0; nf < 8; nf++)
        #pragma unroll
        for (int reg = 0; reg < 4; reg++)
            ks[qw * 16 + quad * 4 + reg][nf * 16 + l15] = bfbits(o[nf][reg]);
    if (l15 == 0) {
        #pragma unroll
        for (int reg = 0; reg < 4; reg++)
            ml[zoff + (size_t)b * Tq + q0 + qw * 16 + quad * 4 + reg] =
                make_float2(mcur[reg], lrow[reg]);
    }
    __syncthreads();
    #pragma unroll
    for (int i = 0; i < 4; i++) {
        int idx = t + i * 256;
        int r = idx >> 4, c = idx & 15;
        *(bf16x8*)&Opart[(zoff + (size_t)b * Tq + q0 + r) * Hq + c * 8] =
            *(bf16x8*)&ks[r][c * 8];
    }
}

// ---------------------------------------------------------------------------
// Kernel 3: merge the two split-K partials -> fp32 output.
// grid (Mq/16), block 256: 16 rows/block, 16 lanes/row.
// ---------------------------------------------------------------------------
__global__ __launch_bounds__(256, 4) void merge_kernel(
    const short* __restrict__ Opart, const float2* __restrict__ ml,
    float* __restrict__ outg)
{
    const int t   = threadIdx.x;
    const int row = blockIdx.x * 16 + (t >> 4);
    const int c   = t & 15;

    float2 p0 = ml[row];
    float2 p1 = ml[Mq + row];
    float m  = fmaxf(p0.x, p1.x);
    float a0 = __expf(p0.x - m);
    float a1 = __expf(p1.x - m);
    float inv = 1.0f / (a0 * p0.y + a1 * p1.y);

    bf16x8 o0 = *(const bf16x8*)&Opart[(size_t)row * Hq + c * 8];
    bf16x8 o1 = *(const bf16x8*)&Opart[((size_t)Mq + row) * Hq + c * 8];

    float4 r0, r1;
    r0.x = (a0 * bf2f(o0[0]) + a1 * bf2f(o1[0])) * inv;
    r0.y = (a0 * bf2f(o0[1]) + a1 * bf2f(o1[1])) * inv;
    r0.z = (a0 * bf2f(o0[2]) + a1 * bf2f(o1[2])) * inv;
    r0.w = (a0 * bf2f(o0[3]) + a1 * bf2f(o1[3])) * inv;
    r1.x = (a0 * bf2f(o0[4]) + a1 * bf2f(o1[4])) * inv;
    r1.y = (a0 * bf2f(o0[5]) + a1 * bf2f(o1[5])) * inv;
    r1.z = (a0 * bf2f(o0[6]) + a1 * bf2f(o1[6])) * inv;
    r1.w = (a0 * bf2f(o0[7]) + a1 * bf2f(o1[7])) * inv;

    float* dst = &outg[(size_t)row * Hq + c * 8];
    *(float4*)dst       = r0;
    *(float4*)(dst + 4) = r1;
}

// ---------------------------------------------------------------------------
extern "C" void kernel_launch(void* const* d_in, const int* in_sizes, int n_in,
                              void* d_out, int out_size, void* d_ws, size_t ws_size,
                              hipStream_t stream) {
    const float* x   = (const float*)d_in[0];
    const float* Wqp = (const float*)d_in[1];
    const float* Wkp = (const float*)d_in[2];
    const float* Wvp = (const float*)d_in[3];
    float* out = (float*)d_out;

    // workspace layout (16B-aligned chunks), total ~21.8 MB
    short* qg    = (short*)d_ws;                        // [Mq][128]        4 MB
    short* kg    = qg  + (size_t)Mq * Hq;               // [Mq][128]        4 MB
    short* vTt   = kg  + (size_t)Mq * Hq;               // [Bq][64][128][64]4 MB
    short* wTg   = vTt + (size_t)Mq * Hq;               // [3][128][2048] 1.5 MB
    short* Opart = wTg + (size_t)3 * 128 * Dq;          // [2][Mq][128]     8 MB
    float2* ml   = (float2*)(Opart + (size_t)2 * Mq * Hq); // [2][Mq]     256 KB

    wt_kernel<<<dim3(16, 3), dim3(256), 0, stream>>>(Wqp, Wkp, Wvp, wTg);
    qkv_mfma_kernel<<<dim3(3, Mq / 128), dim3(256), 0, stream>>>(x, wTg, qg, kg, vTt);
    attn_part_kernel<<<dim3(Tq / 64, Bq, 2), dim3(256), 0, stream>>>(qg, kg, vTt, Opart, ml);
    merge_kernel<<<dim3(Mq / 16), dim3(256), 0, stream>>>(Opart, ml, out);
}

// Round 5
// 319.051 us; speedup vs baseline: 4.1923x; 1.0371x over previous
//
#include <hip/hip_runtime.h>
#include <hip/hip_bf16.h>

// Problem constants (B,T,D,H) = (4,4096,2048,128)
#define Bq 4
#define Tq 4096
#define Dq 2048
#define Hq 128
#define Mq (Bq*Tq)   // 16384 rows
#define CHUNK 16     // k-tiles per attention partial block

typedef __attribute__((ext_vector_type(8))) short bf16x8;
typedef __attribute__((ext_vector_type(4))) float f32x4;

static __device__ __forceinline__ short bfbits(float f) {
    union { __hip_bfloat16 h; short s; } u;
    u.h = __float2bfloat16(f);
    return u.s;
}
static __device__ __forceinline__ float bf2f(short s) {
    union { unsigned u; float f; } v;
    v.u = ((unsigned)(unsigned short)s) << 16;
    return v.f;
}

// ---------------------------------------------------------------------------
// Kernel 0: W transpose+convert.  W[w] fp32 [2048][128] -> wT bf16 [w*128+h][2048].
// Scale 1/sqrt(128) folded into w==0 (Wq).  grid (16,3), block 256.
// ---------------------------------------------------------------------------
__global__ __launch_bounds__(256, 1) void wt_kernel(
    const float* __restrict__ Wqp,
    const float* __restrict__ Wkp,
    const float* __restrict__ Wvp,
    short* __restrict__ wTg)          // [384][2048]
{
    __shared__ short trsp[128][136];
    const int kc = blockIdx.x;
    const int w  = blockIdx.y;
    const float* __restrict__ W = (w == 0) ? Wqp : (w == 1) ? Wkp : Wvp;
    const float scale = (w == 0) ? 0.08838834764831843f : 1.0f;
    const int t = threadIdx.x;

    #pragma unroll
    for (int i = 0; i < 16; i++) {
        int idx = t + i * 256;
        int r = idx >> 5, c4 = idx & 31;
        float4 f = *(const float4*)&W[(size_t)(kc * 128 + r) * Hq + c4 * 4];
        trsp[c4 * 4 + 0][r] = bfbits(f.x * scale);
        trsp[c4 * 4 + 1][r] = bfbits(f.y * scale);
        trsp[c4 * 4 + 2][r] = bfbits(f.z * scale);
        trsp[c4 * 4 + 3][r] = bfbits(f.w * scale);
    }
    __syncthreads();
    #pragma unroll
    for (int i = 0; i < 8; i++) {
        int idx = t + i * 256;
        int h = idx >> 4, c8 = idx & 15;
        *(bf16x8*)&wTg[((size_t)w * 128 + h) * Dq + kc * 128 + c8 * 8] =
            *(bf16x8*)&trsp[h][c8 * 8];
    }
}

// ---------------------------------------------------------------------------
// Kernel 1: FUSED QKV projection, bf16 MFMA.  x read ONCE; N = 384 (q|k|v).
// grid (Mq/64), block 256 = 4 waves; wave covers M64 x N96 (6 n-frags).
// q,k -> row-major bf16 [Mq][128]; v -> TILED transposed vTt[b][jt][128][64].
// ---------------------------------------------------------------------------
__global__ __launch_bounds__(256, 1) void qkv_fused_kernel(
    const float* __restrict__ x,
    const short* __restrict__ wTg,    // [384][2048] bf16
    short* __restrict__ qg,           // [Mq][128]
    short* __restrict__ kg,           // [Mq][128]
    short* __restrict__ vTt)          // [Bq][Tq/64][128][64]
{
    __shared__ short smem[64 * 72 + 384 * 72];        // 64.5 KB
    short (*xs)[72]  = (short(*)[72])smem;            // x tile [m][k]
    short (*wts)[72] = (short(*)[72])(smem + 64 * 72);// W tile [n 0..383][k]

    const int m0 = blockIdx.x * 64;

    const int t    = threadIdx.x;
    const int lane = t & 63;
    const int qw   = t >> 6;
    const int l15  = lane & 15;
    const int quad = lane >> 4;

    f32x4 o[4][6];
    #pragma unroll
    for (int mf = 0; mf < 4; mf++)
        #pragma unroll
        for (int j = 0; j < 6; j++) o[mf][j] = (f32x4){0.f, 0.f, 0.f, 0.f};

    // staging maps
    const int xr = t >> 2, xc = (t & 3) * 16;   // x: 4 lanes/row, 16 floats each

    float4 xreg[4];
    bf16x8 wreg[12];
    // prefetch first tile
    {
        const float* src = x + (size_t)(m0 + xr) * Dq + xc;
        #pragma unroll
        for (int i = 0; i < 4; i++) xreg[i] = *(const float4*)(src + i * 4);
        #pragma unroll
        for (int i = 0; i < 12; i++) {
            int idx = t + i * 256;
            wreg[i] = *(const bf16x8*)&wTg[(size_t)(idx >> 3) * Dq + (idx & 7) * 8];
        }
    }

    for (int k0 = 0; k0 < Dq; k0 += 64) {
        __syncthreads();
        // write prefetched tile to LDS (x: cvt fp32->bf16)
        {
            bf16x8 v0, v1;
            v0[0] = bfbits(xreg[0].x); v0[1] = bfbits(xreg[0].y);
            v0[2] = bfbits(xreg[0].z); v0[3] = bfbits(xreg[0].w);
            v0[4] = bfbits(xreg[1].x); v0[5] = bfbits(xreg[1].y);
            v0[6] = bfbits(xreg[1].z); v0[7] = bfbits(xreg[1].w);
            v1[0] = bfbits(xreg[2].x); v1[1] = bfbits(xreg[2].y);
            v1[2] = bfbits(xreg[2].z); v1[3] = bfbits(xreg[2].w);
            v1[4] = bfbits(xreg[3].x); v1[5] = bfbits(xreg[3].y);
            v1[6] = bfbits(xreg[3].z); v1[7] = bfbits(xreg[3].w);
            *(bf16x8*)&xs[xr][xc]     = v0;
            *(bf16x8*)&xs[xr][xc + 8] = v1;
            #pragma unroll
            for (int i = 0; i < 12; i++) {
                int idx = t + i * 256;
                *(bf16x8*)&wts[idx >> 3][(idx & 7) * 8] = wreg[i];
            }
        }
        // prefetch next tile
        if (k0 + 64 < Dq) {
            const float* src = x + (size_t)(m0 + xr) * Dq + k0 + 64 + xc;
            #pragma unroll
            for (int i = 0; i < 4; i++) xreg[i] = *(const float4*)(src + i * 4);
            #pragma unroll
            for (int i = 0; i < 12; i++) {
                int idx = t + i * 256;
                wreg[i] = *(const bf16x8*)&wTg[(size_t)(idx >> 3) * Dq + k0 + 64 + (idx & 7) * 8];
            }
        }
        __syncthreads();

        #pragma unroll
        for (int kk = 0; kk < 2; kk++) {
            bf16x8 a[4], b[6];
            #pragma unroll
            for (int mf = 0; mf < 4; mf++)
                a[mf] = *(bf16x8*)&xs[mf * 16 + l15][kk * 32 + quad * 8];
            #pragma unroll
            for (int j = 0; j < 6; j++)
                b[j] = *(bf16x8*)&wts[(qw * 6 + j) * 16 + l15][kk * 32 + quad * 8];
            #pragma unroll
            for (int mf = 0; mf < 4; mf++)
                #pragma unroll
                for (int j = 0; j < 6; j++)
                    o[mf][j] = __builtin_amdgcn_mfma_f32_16x16x32_bf16(
                        a[mf], b[j], o[mf][j], 0, 0, 0);
        }
    }

    // ---- epilogue phase 1: q,k row-major via LDS e64[64][264] ----
    __syncthreads();
    {
        short (*e64)[264] = (short(*)[264])smem;
        #pragma unroll
        for (int mf = 0; mf < 4; mf++)
            #pragma unroll
            for (int j = 0; j < 6; j++) {
                int n0 = (qw * 6 + j) * 16;
                if (n0 < 256) {
                    #pragma unroll
                    for (int reg = 0; reg < 4; reg++)
                        e64[mf * 16 + quad * 4 + reg][n0 + l15] = bfbits(o[mf][j][reg]);
                }
            }
        __syncthreads();
        #pragma unroll
        for (int i = 0; i < 8; i++) {
            int idx = t + i * 256;          // 64 rows x 32 16B-units
            int r = idx >> 5, u = idx & 31;
            int n = u * 8;
            bf16x8 val = *(bf16x8*)&e64[r][n];
            short* dst = (n < 128) ? &qg[(size_t)(m0 + r) * Hq + n]
                                   : &kg[(size_t)(m0 + r) * Hq + (n - 128)];
            *(bf16x8*)dst = val;
        }
    }
    // ---- epilogue phase 2: v transposed via LDS e128[128][72] ----
    __syncthreads();
    {
        short (*e128)[72] = (short(*)[72])smem;
        #pragma unroll
        for (int mf = 0; mf < 4; mf++)
            #pragma unroll
            for (int j = 0; j < 6; j++) {
                int n0 = (qw * 6 + j) * 16;
                if (n0 >= 256) {
                    short4 pk;
                    pk.x = bfbits(o[mf][j][0]); pk.y = bfbits(o[mf][j][1]);
                    pk.z = bfbits(o[mf][j][2]); pk.w = bfbits(o[mf][j][3]);
                    *(short4*)&e128[(n0 - 256) + l15][mf * 16 + quad * 4] = pk;
                }
            }
        __syncthreads();
        const int bb = m0 / Tq;
        const int jt = (m0 % Tq) >> 6;
        #pragma unroll
        for (int i = 0; i < 4; i++) {
            int idx = t + i * 256;          // 128 rows x 8 16B-units
            int h = idx >> 3, u = idx & 7;
            *(bf16x8*)&vTt[(((size_t)bb * (Tq / 64) + jt) * 128 + h) * 64 + u * 8] =
                *(bf16x8*)&e128[h][u * 8];
        }
    }
}

// ---------------------------------------------------------------------------
// Kernel 2: causal flash attention partials, balanced chunks of CHUNK k-tiles.
// grid (Tq/64, Bq, 4).  Block (qt,b,c) does key-tiles [16c, min(qt+1,16c+16));
// invalid blocks exit.  Partials (unnormalized O bf16, m/l fp32) merged later.
// ---------------------------------------------------------------------------
__global__ __launch_bounds__(256, 2) void attn_part_kernel(
    const short* __restrict__ qg, const short* __restrict__ kg,
    const short* __restrict__ vTt,
    short* __restrict__ Opart,        // [4][Mq][128] bf16 (unnormalized)
    float2* __restrict__ ml)          // [4][Mq] (m, l)
{
    __shared__ short qs[64][136];
    __shared__ short ks[64][136];
    __shared__ short vt[128][72];
    __shared__ short ps[64][72];

    const int qt = blockIdx.x;
    const int b  = blockIdx.y;
    const int c  = blockIdx.z;
    const int q0 = qt * 64;

    const int lo = c * CHUNK;
    const int hi = min(qt + 1, lo + CHUNK);
    if (lo >= hi) return;

    const int t    = threadIdx.x;
    const int lane = t & 63;
    const int qw   = t >> 6;
    const int l15  = lane & 15;
    const int quad = lane >> 4;

    const size_t zoff = (size_t)c * Mq;

    // stage Q tile
    #pragma unroll
    for (int i = 0; i < 4; i++) {
        int idx = t + i * 256;
        int r = idx >> 4, cc = idx & 15;
        *(bf16x8*)&qs[r][cc * 8] =
            *(const bf16x8*)&qg[(size_t)(b * Tq + q0 + r) * Hq + cc * 8];
    }

    float mcur[4], lrow[4];
    #pragma unroll
    for (int r = 0; r < 4; r++) { mcur[r] = -1e30f; lrow[r] = 0.f; }
    f32x4 o[8];
    #pragma unroll
    for (int nf = 0; nf < 8; nf++) o[nf] = (f32x4){0.f, 0.f, 0.f, 0.f};

    // register prefetch of first K/V tile
    bf16x8 kreg[4], vreg[4];
    {
        const size_t kbase = (size_t)(b * Tq + lo * 64) * Hq;
        const short* vsrc = vTt + (((size_t)b * (Tq / 64) + lo) * 128) * 64;
        #pragma unroll
        for (int i = 0; i < 4; i++) {
            int idx = t + i * 256;
            kreg[i] = *(const bf16x8*)&kg[kbase + (size_t)(idx >> 4) * Hq + (idx & 15) * 8];
            vreg[i] = *(const bf16x8*)&vsrc[idx * 8];
        }
    }

    for (int jt = lo; jt < hi; jt++) {
        __syncthreads();

        #pragma unroll
        for (int i = 0; i < 4; i++) {
            int idx = t + i * 256;
            *(bf16x8*)&ks[idx >> 4][(idx & 15) * 8] = kreg[i];
            *(bf16x8*)&vt[idx >> 3][(idx & 7) * 8]  = vreg[i];
        }
        if (jt + 1 < hi) {
            const size_t kbase = (size_t)(b * Tq + (jt + 1) * 64) * Hq;
            const short* vsrc = vTt + (((size_t)b * (Tq / 64) + jt + 1) * 128) * 64;
            #pragma unroll
            for (int i = 0; i < 4; i++) {
                int idx = t + i * 256;
                kreg[i] = *(const bf16x8*)&kg[kbase + (size_t)(idx >> 4) * Hq + (idx & 15) * 8];
                vreg[i] = *(const bf16x8*)&vsrc[idx * 8];
            }
        }
        __syncthreads();

        // S = Q K^T
        f32x4 sacc[4];
        #pragma unroll
        for (int nf = 0; nf < 4; nf++) sacc[nf] = (f32x4){0.f, 0.f, 0.f, 0.f};
        #pragma unroll
        for (int kk = 0; kk < 4; kk++) {
            bf16x8 aq = *(bf16x8*)&qs[qw * 16 + l15][kk * 32 + quad * 8];
            #pragma unroll
            for (int nf = 0; nf < 4; nf++) {
                bf16x8 bk = *(bf16x8*)&ks[nf * 16 + l15][kk * 32 + quad * 8];
                sacc[nf] = __builtin_amdgcn_mfma_f32_16x16x32_bf16(aq, bk, sacc[nf], 0, 0, 0);
            }
        }

        const bool diag = (jt == qt);
        #pragma unroll
        for (int reg = 0; reg < 4; reg++) {
            const int rloc = qw * 16 + quad * 4 + reg;
            if (diag) {
                #pragma unroll
                for (int nf = 0; nf < 4; nf++)
                    if (nf * 16 + l15 > rloc) sacc[nf][reg] = -1e30f;
            }
            float m_r = fmaxf(fmaxf(sacc[0][reg], sacc[1][reg]),
                              fmaxf(sacc[2][reg], sacc[3][reg]));
            #pragma unroll
            for (int mm = 8; mm >= 1; mm >>= 1)
                m_r = fmaxf(m_r, __shfl_xor(m_r, mm, 16));
            float mnew  = fmaxf(mcur[reg], m_r);
            float alpha = __expf(mcur[reg] - mnew);
            mcur[reg]   = mnew;
            float rs = 0.f;
            #pragma unroll
            for (int nf = 0; nf < 4; nf++) {
                float p = __expf(sacc[nf][reg] - mnew);
                rs += p;
                ps[rloc][nf * 16 + l15] = bfbits(p);
            }
            #pragma unroll
            for (int mm = 8; mm >= 1; mm >>= 1)
                rs += __shfl_xor(rs, mm, 16);
            lrow[reg] = lrow[reg] * alpha + rs;
            #pragma unroll
            for (int nf = 0; nf < 8; nf++) o[nf][reg] *= alpha;
        }
        __threadfence_block();

        // O += P V
        #pragma unroll
        for (int ks2 = 0; ks2 < 2; ks2++) {
            bf16x8 ap = *(bf16x8*)&ps[qw * 16 + l15][ks2 * 32 + quad * 8];
            #pragma unroll
            for (int nf = 0; nf < 8; nf++) {
                bf16x8 bv = *(bf16x8*)&vt[nf * 16 + l15][ks2 * 32 + quad * 8];
                o[nf] = __builtin_amdgcn_mfma_f32_16x16x32_bf16(ap, bv, o[nf], 0, 0, 0);
            }
        }
    }

    // epilogue: unnormalized bf16 partial via LDS transpose (reuse ks)
    __syncthreads();
    #pragma unroll
    for (int nf = 0; nf < 8; nf++)
        #pragma unroll
        for (int reg = 0; reg < 4; reg++)
            ks[qw * 16 + quad * 4 + reg][nf * 16 + l15] = bfbits(o[nf][reg]);
    if (l15 == 0) {
        #pragma unroll
        for (int reg = 0; reg < 4; reg++)
            ml[zoff + (size_t)b * Tq + q0 + qw * 16 + quad * 4 + reg] =
                make_float2(mcur[reg], lrow[reg]);
    }
    __syncthreads();
    #pragma unroll
    for (int i = 0; i < 4; i++) {
        int idx = t + i * 256;
        int r = idx >> 4, cc = idx & 15;
        *(bf16x8*)&Opart[(zoff + (size_t)b * Tq + q0 + r) * Hq + cc * 8] =
            *(bf16x8*)&ks[r][cc * 8];
    }
}

// ---------------------------------------------------------------------------
// Kernel 3: merge up to 4 partials -> fp32 output.
// grid (Mq/16), block 256: 16 rows/block, 16 lanes/row.
// ---------------------------------------------------------------------------
__global__ __launch_bounds__(256, 4) void merge_kernel(
    const short* __restrict__ Opart, const float2* __restrict__ ml,
    float* __restrict__ outg)
{
    const int t   = threadIdx.x;
    const int row = blockIdx.x * 16 + (t >> 4);
    const int cu  = t & 15;

    const int rl  = row & (Tq - 1);
    const int nch = (rl >> 10) + 1;     // = ceil((qt+1)/CHUNK), qt = rl>>6

    float m = ml[row].x;
    for (int cc = 1; cc < nch; cc++) m = fmaxf(m, ml[(size_t)cc * Mq + row].x);

    float lsum = 0.f;
    float acc[8] = {};
    for (int cc = 0; cc < nch; cc++) {
        float2 p = ml[(size_t)cc * Mq + row];
        float a = __expf(p.x - m);
        lsum += a * p.y;
        bf16x8 oc = *(const bf16x8*)&Opart[((size_t)cc * Mq + row) * Hq + cu * 8];
        #pragma unroll
        for (int j = 0; j < 8; j++) acc[j] += a * bf2f(oc[j]);
    }
    float inv = 1.0f / lsum;

    float4 r0, r1;
    r0.x = acc[0] * inv; r0.y = acc[1] * inv; r0.z = acc[2] * inv; r0.w = acc[3] * inv;
    r1.x = acc[4] * inv; r1.y = acc[5] * inv; r1.z = acc[6] * inv; r1.w = acc[7] * inv;
    float* dst = &outg[(size_t)row * Hq + cu * 8];
    *(float4*)dst       = r0;
    *(float4*)(dst + 4) = r1;
}

// ---------------------------------------------------------------------------
extern "C" void kernel_launch(void* const* d_in, const int* in_sizes, int n_in,
                              void* d_out, int out_size, void* d_ws, size_t ws_size,
                              hipStream_t stream) {
    const float* x   = (const float*)d_in[0];
    const float* Wqp = (const float*)d_in[1];
    const float* Wkp = (const float*)d_in[2];
    const float* Wvp = (const float*)d_in[3];
    float* out = (float*)d_out;

    // workspace layout (~28.5 MB):
    //  [qg 4MB][kg 4MB][vTt 4MB][Opart 16MB][ml 512KB]
    //  wTg (1.5MB) overlays Opart[0] — dead after qkv_fused, before attn writes.
    short* qg    = (short*)d_ws;
    short* kg    = qg  + (size_t)Mq * Hq;
    short* vTt   = kg  + (size_t)Mq * Hq;
    short* Opart = vTt + (size_t)Mq * Hq;
    short* wTg   = Opart;                                 // overlay
    float2* ml   = (float2*)(Opart + (size_t)4 * Mq * Hq);

    wt_kernel<<<dim3(16, 3), dim3(256), 0, stream>>>(Wqp, Wkp, Wvp, wTg);
    qkv_fused_kernel<<<dim3(Mq / 64), dim3(256), 0, stream>>>(x, wTg, qg, kg, vTt);
    attn_part_kernel<<<dim3(Tq / 64, Bq, 4), dim3(256), 0, stream>>>(qg, kg, vTt, Opart, ml);
    merge_kernel<<<dim3(Mq / 16), dim3(256), 0, stream>>>(Opart, ml, out);
}